// Round 11
// baseline (270.303 us; speedup 1.0000x reference)
//
#include <hip/hip_runtime.h>

#define NFEAT 64
#define BSHIFT 8
#define BCOLS 256              // cols/rows per bucket = 1<<BSHIFT
#define NBMAX 512              // array size >= nbuck = ceil(100000/256) = 391
#define CAP 5120               // per-bucket capacity (mean 4092 + 16 sigma)
#define CHUNK 3136             // edges per partition chunk (511 chunks)
#define NITP 7                 // ceil(CHUNK/TPB) reg-cached entries per thread
#define TPB 512                // threads per block (8 waves)
#define FBIT (CAP / TPB)       // 10 reg-cached entries per fuse scan thread
#define QCAP 1664              // per-quarter stage capacity (mean 1024 + 20 sigma)

// ---------------------------------------------------------------------------
// MEASUREMENT ROUND, take 2. r10's rep-loop partition raced: reps wrote the
// SAME part[]/partR[] with different permutations concurrently -> corrupted
// multiset (absmax 1.66). Fix: reps 0-1 write DUMMY part/partR buffers in ws;
// rep 2 (own cursor set) writes the real ones == verified single-pass
// partition. Work per rep byte-identical, only dst base differs.
//   k_partCR3 : 3 reps (reps 0-1 -> partDummy, rep 2 -> part)
//   k_fillR5  : 5 reps (idempotent)
//   k_fuse3   : 3 reps (reps 0-1 -> outDummy, rep 2 -> out)
// dur_us sacrificial; goal = per-phase dur+counters in top-5 (each dispatch
// must exceed the ~43.5us fillBuffer poison line).
// ---------------------------------------------------------------------------

__device__ __forceinline__ unsigned short f2bf(float f) {
    unsigned int u = __float_as_uint(f);
    return (unsigned short)((u + 0x7FFFu + ((u >> 16) & 1u)) >> 16);  // RNE
}
__device__ __forceinline__ float bflo(unsigned int u) {
    return __uint_as_float(u << 16);
}
__device__ __forceinline__ float bfhi(unsigned int u) {
    return __uint_as_float(u & 0xFFFF0000u);
}

__device__ __forceinline__ int wave_incl_scan(int v, int lane) {
    #pragma unroll
    for (int off = 1; off < 64; off <<= 1) {
        int u = __shfl_up(v, off);
        if (lane >= off) v += u;
    }
    return v;
}

// fused dual partition, x3 reps (rep-indexed cursors; reps 0-1 -> dummy dst)
__global__ __launch_bounds__(TPB)
void k_partCR3(const int* __restrict__ rows, const int* __restrict__ cols,
               int* __restrict__ bcurAll, int* __restrict__ bcurRAll,
               int* __restrict__ partDummy, unsigned char* __restrict__ partRDummy,
               int* __restrict__ part, unsigned char* __restrict__ partR, int E) {
    __shared__ int histC[NBMAX];
    __shared__ int histR[NBMAX];
    __shared__ int gbaseC[NBMAX];
    __shared__ int gbaseR[NBMAX];
    __shared__ int wsumC[8];
    __shared__ int wsumR[8];
    __shared__ int stageC[CHUNK];
    __shared__ unsigned char stageR[CHUNK];
    __shared__ unsigned short bidC[CHUNK];
    __shared__ unsigned short bidR[CHUNK];
    int chunk0 = blockIdx.x * CHUNK;
    int cnt = min(CHUNK, E - chunk0);
    int t = threadIdx.x;           // TPB = 512
    int lane = t & 63, wid = t >> 6;

    for (int rep = 0; rep < 3; rep++) {
        int* bcur  = bcurAll  + rep * NBMAX;
        int* bcurR = bcurRAll + rep * NBMAX;
        int* dstP  = (rep == 2) ? part  : partDummy;
        unsigned char* dstR = (rep == 2) ? partR : partRDummy;
        __syncthreads();
        histC[t] = 0; histR[t] = 0;
        __syncthreads();

        // ---- count phase: rank = atomicAdd return ----
        int pk[NITP];
        unsigned char rpk[NITP];
        unsigned short cb[NITP], rb[NITP];
        unsigned short rkC[NITP], rkR[NITP];
        #pragma unroll
        for (int k = 0; k < NITP; k++) {
            int i = t + k * TPB;
            if (i < cnt) {
                int c = cols[chunk0 + i];
                int r = rows[chunk0 + i];
                int b  = c >> BSHIFT;
                int b2 = r >> BSHIFT;
                pk[k]  = ((c & (BCOLS - 1)) << 17) | r;
                rpk[k] = (unsigned char)(r & (BCOLS - 1));
                cb[k] = (unsigned short)b;
                rb[k] = (unsigned short)b2;
                rkC[k] = (unsigned short)atomicAdd(&histC[b], 1);
                rkR[k] = (unsigned short)atomicAdd(&histR[b2], 1);
            }
        }
        __syncthreads();

        // ---- two 512-bin scans + global cursor alloc ----
        int v1 = histC[t];
        int inc1 = wave_incl_scan(v1, lane);
        if (lane == 63) wsumC[wid] = inc1;
        int v2 = histR[t];
        int inc2 = wave_incl_scan(v2, lane);
        if (lane == 63) wsumR[wid] = inc2;
        __syncthreads();
        int addC = 0, addR = 0;
        #pragma unroll
        for (int k = 0; k < 8; k++) {
            if (k < wid) { addC += wsumC[k]; addR += wsumR[k]; }
        }
        int exC = inc1 - v1 + addC;
        int exR = inc2 - v2 + addR;
        gbaseC[t] = (v1 > 0) ? (t * CAP + atomicAdd(&bcur[t],  v1) - exC) : 0;
        gbaseR[t] = (v2 > 0) ? (t * CAP + atomicAdd(&bcurR[t], v2) - exR) : 0;
        histC[t] = exC;                // scan base for scatter
        histR[t] = exR;
        __syncthreads();

        // ---- scatter phase: scan base + saved rank ----
        #pragma unroll
        for (int k = 0; k < NITP; k++) {
            int i = t + k * TPB;
            if (i < cnt) {
                int p = histC[cb[k]] + rkC[k];
                stageC[p] = pk[k];
                bidC[p] = cb[k];
                int p2 = histR[rb[k]] + rkR[k];
                stageR[p2] = rpk[k];
                bidR[p2] = rb[k];
            }
        }
        __syncthreads();

        // ---- coalesced global write (rep-selected destination) ----
        for (int p = t; p < cnt; p += TPB) {
            int b = bidC[p];
            int idx = gbaseC[b] + p;
            if (idx < (b + 1) * CAP) dstP[idx] = stageC[p];    // overflow clamp
            int b2 = bidR[p];
            int idx2 = gbaseR[b2] + p;
            if (idx2 < (b2 + 1) * CAP) dstR[idx2] = stageR[p];
        }
    }
}

// per QUARTER-bucket (64 rows): count partR (uchar4) -> dinv + xs, x5 reps
__global__ __launch_bounds__(TPB)
void k_fillR5(const unsigned char* __restrict__ partR, const int* __restrict__ bcurR,
              const float4* __restrict__ x4, float* __restrict__ dinv,
              unsigned short* __restrict__ xs, int n) {
    __shared__ int lcnt[64];
    __shared__ float ldinv[64];
    int qb = blockIdx.x;
    int b = qb >> 2, q = qb & 3;
    int s = b * CAP;               // CAP multiple of 4 -> uchar4-aligned
    int t = threadIdx.x;           // TPB = 512
    int cntR = min(bcurR[b], CAP);
    int rows_base = (b << BSHIFT) + (q << 6);

    for (int rep = 0; rep < 5; rep++) {
        __syncthreads();
        if (t < 64) lcnt[t] = 0;
        __syncthreads();
        int c4 = cntR >> 2;
        const uchar4* p4 = (const uchar4*)(partR + s);
        for (int i = t; i < c4; i += TPB) {
            uchar4 kk = p4[i];
            if ((kk.x >> 6) == q) atomicAdd(&lcnt[kk.x & 63], 1);
            if ((kk.y >> 6) == q) atomicAdd(&lcnt[kk.y & 63], 1);
            if ((kk.z >> 6) == q) atomicAdd(&lcnt[kk.z & 63], 1);
            if ((kk.w >> 6) == q) atomicAdd(&lcnt[kk.w & 63], 1);
        }
        for (int i = (c4 << 2) + t; i < cntR; i += TPB) {
            int key = partR[s + i];
            if ((key >> 6) == q) atomicAdd(&lcnt[key & 63], 1);
        }
        __syncthreads();
        if (t < 64) {
            float d = rsqrtf((float)(lcnt[t] + 1));      // +1 self loop
            ldinv[t] = d;
            int gr = rows_base + t;
            if (gr < n) dinv[gr] = d;
        }
        __syncthreads();
        int nr = n - rows_base;
        if (nr > 0) {
            size_t base4 = (size_t)rows_base << 4;       // float4 idx
            int lim = min(64, nr) << 4;
            for (int i = t; i < lim; i += TPB) {
                float dd = ldinv[i >> 4];
                float4 vv = x4[base4 + i];
                ushort4 o;
                o.x = f2bf(dd * vv.x); o.y = f2bf(dd * vv.y);
                o.z = f2bf(dd * vv.z); o.w = f2bf(dd * vv.w);
                ((ushort4*)xs)[base4 + i] = o;
            }
        }
    }
}

#define XSLD(r) (*((const uint4*)(xs + ((size_t)(r) << 6)) + li))
#define ACC8(u) { a0 += bflo(u.x); a1 += bfhi(u.x); \
                  a2 += bflo(u.y); a3 += bfhi(u.y); \
                  a4 += bflo(u.z); a5 += bfhi(u.z); \
                  a6 += bflo(u.w); a7 += bfhi(u.w); }

// per QUARTER-bucket: CSR + gather, x3 reps (reps 0-1 -> dummy out)
__global__ __launch_bounds__(TPB)
void k_fuse3(const int* __restrict__ part, const int* __restrict__ bcur,
             const unsigned short* __restrict__ xs,
             const float* __restrict__ dinv,
             float4* __restrict__ dummy4, float4* __restrict__ out4, int n) {
    __shared__ int lcnt[64];
    __shared__ int lps[64];
    __shared__ int stage[QCAP];        // 6.5KB
    int qb = blockIdx.x;
    int b = qb >> 2, q = qb & 3;
    int s = b * CAP;
    int cnt = min(bcur[b], CAP);
    int t = threadIdx.x;           // TPB = 512

    for (int rep = 0; rep < 3; rep++) {
        float4* dst4 = (rep == 2) ? out4 : dummy4;
        __syncthreads();
        if (t < 64) lcnt[t] = 0;
        __syncthreads();

        // ---- scan + count own quarter (rank = atomic return) ----
        int pk[FBIT];
        short rk[FBIT];
        #pragma unroll
        for (int k = 0; k < FBIT; k++) {
            int i = t + k * TPB;
            int v2 = (i < cnt) ? part[s + i] : -1;
            pk[k] = v2;
            rk[k] = -1;
            if (v2 >= 0) {
                int c = v2 >> 17;              // 0..255 col-low
                if ((c >> 6) == q)
                    rk[k] = (short)atomicAdd(&lcnt[c & 63], 1);
            }
        }
        __syncthreads();

        // ---- 64-bin scan by wave 0 ----
        if (t < 64) {
            int v = lcnt[t];
            int inc = wave_incl_scan(v, t);
            lps[t] = inc - v;
        }
        __syncthreads();

        // ---- scatter own quarter: NO atomics ----
        #pragma unroll
        for (int k = 0; k < FBIT; k++) {
            if (rk[k] >= 0) {
                int c = (pk[k] >> 17) & 63;
                int p = lps[c] + rk[k];
                if (p < QCAP) stage[p] = pk[k] & 0x1FFFF;   // pure row id
            }
        }
        __syncthreads();

        // ---- gather: 64 groups x 8 lanes; group g owns col q*64+g ----
        int g = t >> 3, li = t & 7;
        int node = (b << BSHIFT) + (q << 6) + g;
        if (node < n) {                       // guard (no return: rep barriers)
            int ss = lps[g];
            int len = lcnt[g];
            if (ss + len > QCAP) len = QCAP > ss ? QCAP - ss : 0;  // clamp
            float a0 = 0.f, a1 = 0.f, a2 = 0.f, a3 = 0.f;
            float a4 = 0.f, a5 = 0.f, a6 = 0.f, a7 = 0.f;
            int len4 = len & ~3;
            uint4 c0, c1, c2, c3;
            if (len4 > 0) {
                int r0 = stage[ss], r1 = stage[ss + 1];
                int r2 = stage[ss + 2], r3 = stage[ss + 3];
                c0 = XSLD(r0); c1 = XSLD(r1); c2 = XSLD(r2); c3 = XSLD(r3);
            }
            for (int i = 4; i < len4; i += 4) {
                int r0 = stage[ss + i],     r1 = stage[ss + i + 1];
                int r2 = stage[ss + i + 2], r3 = stage[ss + i + 3];
                uint4 n0 = XSLD(r0), n1 = XSLD(r1);
                uint4 n2 = XSLD(r2), n3 = XSLD(r3);
                ACC8(c0); ACC8(c1); ACC8(c2); ACC8(c3);
                c0 = n0; c1 = n1; c2 = n2; c3 = n3;
            }
            if (len4 > 0) { ACC8(c0); ACC8(c1); ACC8(c2); ACC8(c3); }
            for (int i = len4; i < len; i++) {
                int r = stage[ss + i];
                uint4 u = XSLD(r);
                ACC8(u);
            }
            // self term + scale + store
            float dc = dinv[node];
            uint4 us = XSLD(node);
            float4 r0o, r1o;
            r0o.x = dc * (a0 + bflo(us.x));
            r0o.y = dc * (a1 + bfhi(us.x));
            r0o.z = dc * (a2 + bflo(us.y));
            r0o.w = dc * (a3 + bfhi(us.y));
            r1o.x = dc * (a4 + bflo(us.z));
            r1o.y = dc * (a5 + bfhi(us.z));
            r1o.z = dc * (a6 + bflo(us.w));
            r1o.w = dc * (a7 + bfhi(us.w));
            size_t ob = ((size_t)node << 4) + (li << 1);
            dst4[ob] = r0o;
            dst4[ob + 1] = r1o;
        }
    }
}

extern "C" void kernel_launch(void* const* d_in, const int* in_sizes, int n_in,
                              void* d_out, int out_size, void* d_ws, size_t ws_size,
                              hipStream_t stream) {
    const float* x    = (const float*)d_in[0];
    const int*   eidx = (const int*)d_in[1];   // int32 (JAX x64 disabled)

    int n = in_sizes[0] / NFEAT;               // 100000
    int E = in_sizes[1] / 2;                   // 1600000
    const int* rows = eidx;
    const int* cols = eidx + E;
    float* out = (float*)d_out;

    int nbuck = (n + BCOLS - 1) >> BSHIFT;     // 391

    // ws: bcur3[3*NBMAX] | bcurR3[3*NBMAX] | dinv[n] | xs[n*64 bf16]
    //     | part | partR | partDummy | partRDummy | outDummy[n*64 f32]
    char* w = (char*)d_ws;
    int*   bcur3  = (int*)w;    w += 3 * NBMAX * 4;
    int*   bcurR3 = (int*)w;    w += 3 * NBMAX * 4;
    float* dinv  = (float*)w;   w += (size_t)n * 4;
    w = (char*)(((uintptr_t)w + 15) & ~(uintptr_t)15);
    unsigned short* xs = (unsigned short*)w;  w += (size_t)n * NFEAT * 2;
    int*   part  = (int*)w;     w += (size_t)nbuck * CAP * 4;
    unsigned char* partR = (unsigned char*)w; w += (size_t)nbuck * CAP;
    w = (char*)(((uintptr_t)w + 15) & ~(uintptr_t)15);
    int*   partDummy = (int*)w; w += (size_t)nbuck * CAP * 4;
    unsigned char* partRDummy = (unsigned char*)w; w += (size_t)nbuck * CAP;
    w = (char*)(((uintptr_t)w + 15) & ~(uintptr_t)15);
    float* outDummy = (float*)w;               // n*64 f32 = 25.6MB scratch

    // zero all 3 cursor pairs — graph-capturable
    hipMemsetAsync(bcur3, 0, 6 * NBMAX * 4, stream);

    int nchunk = (E + CHUNK - 1) / CHUNK;      // 511
    k_partCR3<<<nchunk, TPB, 0, stream>>>(rows, cols, bcur3, bcurR3,
                                          partDummy, partRDummy,
                                          part, partR, E);
    k_fillR5<<<nbuck * 4, TPB, 0, stream>>>(partR, bcurR3, (const float4*)x,
                                            dinv, xs, n);
    k_fuse3<<<nbuck * 4, TPB, 0, stream>>>(part, bcur3, xs, dinv,
                                           (float4*)outDummy, (float4*)out, n);
}

// Round 12
// 142.553 us; speedup vs baseline: 1.8962x; 1.8962x over previous
//
#include <hip/hip_runtime.h>

#define NFEAT 64
#define BSHIFT 8
#define BCOLS 256              // cols/rows per bucket = 1<<BSHIFT
#define NBMAX 512              // array size >= nbuck = ceil(100000/256) = 391
#define CAP 5120               // per-bucket capacity (mean 4092 + 16 sigma)
#define CHUNK 3136             // edges per partition chunk (511 chunks)
#define NITP 7                 // ceil(CHUNK/TPB) reg-cached entries per thread
#define TPB 512                // threads per block (8 waves)
#define FBIT (CAP / TPB)       // 10 reg-cached entries per fuse scan thread

// ---------------------------------------------------------------------------
// out[c,f] = dinv[c]^2 x[c,f] + dinv[c] * sum_{e: col==c} dinv[row_e] x[row_e,f]
// dinv[i] = rsqrt(1 + deg_row[i])
//
// MEASURED BUDGET (r11 rep-probe + r9 system of equations):
//   fixed harness overhead ~84us (256MB ws poison @78% HBM peak + graph tax)
//   partCR ~10us | fillR ~5us | fuse ~43.6us (VALU 29%, occ 38%, 2.72 TB/s)
// Fuse's 2.7 TB/s matches r0's independent implementation (2.78) -> HW
// ceiling for random-128B-row L3 gather; its 84MB L2-miss fetch matches the
// per-XCD distinct-row coverage bound (~88MB). Row-partials / fp8 net <=0.
// This build consolidates the best measured config: full-bucket fillR+fuse
// (single part/partR scan, -27MB redundant reads vs quarter blocks),
// rank-reuse CSR (atomic return = scatter rank), 4-deep MLP gather.
// ---------------------------------------------------------------------------

__device__ __forceinline__ unsigned short f2bf(float f) {
    unsigned int u = __float_as_uint(f);
    return (unsigned short)((u + 0x7FFFu + ((u >> 16) & 1u)) >> 16);  // RNE
}
__device__ __forceinline__ float bflo(unsigned int u) {
    return __uint_as_float(u << 16);
}
__device__ __forceinline__ float bfhi(unsigned int u) {
    return __uint_as_float(u & 0xFFFF0000u);
}

__device__ __forceinline__ int wave_incl_scan(int v, int lane) {
    #pragma unroll
    for (int off = 1; off < 64; off <<= 1) {
        int u = __shfl_up(v, off);
        if (lane >= off) v += u;
    }
    return v;
}

// fused dual partition: col-buckets (int entries) + row-buckets (uchar).
// Count atomic returns rank; scatter = scan-base + rank (plain ds_write).
__global__ __launch_bounds__(TPB)
void k_partCR(const int* __restrict__ rows, const int* __restrict__ cols,
              int* __restrict__ bcur, int* __restrict__ bcurR,
              int* __restrict__ part, unsigned char* __restrict__ partR, int E) {
    __shared__ int histC[NBMAX];
    __shared__ int histR[NBMAX];
    __shared__ int gbaseC[NBMAX];
    __shared__ int gbaseR[NBMAX];
    __shared__ int wsumC[8];
    __shared__ int wsumR[8];
    __shared__ int stageC[CHUNK];
    __shared__ unsigned char stageR[CHUNK];
    __shared__ unsigned short bidC[CHUNK];
    __shared__ unsigned short bidR[CHUNK];
    int chunk0 = blockIdx.x * CHUNK;
    int cnt = min(CHUNK, E - chunk0);
    int t = threadIdx.x;           // TPB = 512
    int lane = t & 63, wid = t >> 6;

    histC[t] = 0; histR[t] = 0;
    __syncthreads();

    // ---- count phase: rank = atomicAdd return ----
    int pk[NITP];
    unsigned char rpk[NITP];
    unsigned short cb[NITP], rb[NITP];
    unsigned short rkC[NITP], rkR[NITP];
    #pragma unroll
    for (int k = 0; k < NITP; k++) {
        int i = t + k * TPB;
        if (i < cnt) {
            int c = cols[chunk0 + i];
            int r = rows[chunk0 + i];
            int b  = c >> BSHIFT;
            int b2 = r >> BSHIFT;
            pk[k]  = ((c & (BCOLS - 1)) << 17) | r;
            rpk[k] = (unsigned char)(r & (BCOLS - 1));
            cb[k] = (unsigned short)b;
            rb[k] = (unsigned short)b2;
            rkC[k] = (unsigned short)atomicAdd(&histC[b], 1);
            rkR[k] = (unsigned short)atomicAdd(&histR[b2], 1);
        }
    }
    __syncthreads();

    // ---- two 512-bin scans + global cursor alloc ----
    int v1 = histC[t];
    int inc1 = wave_incl_scan(v1, lane);
    if (lane == 63) wsumC[wid] = inc1;
    int v2 = histR[t];
    int inc2 = wave_incl_scan(v2, lane);
    if (lane == 63) wsumR[wid] = inc2;
    __syncthreads();
    int addC = 0, addR = 0;
    #pragma unroll
    for (int k = 0; k < 8; k++) {
        if (k < wid) { addC += wsumC[k]; addR += wsumR[k]; }
    }
    int exC = inc1 - v1 + addC;
    int exR = inc2 - v2 + addR;
    // cursors zero-based; absolute base = t*CAP + offset (memset-init'd)
    gbaseC[t] = (v1 > 0) ? (t * CAP + atomicAdd(&bcur[t],  v1) - exC) : 0;
    gbaseR[t] = (v2 > 0) ? (t * CAP + atomicAdd(&bcurR[t], v2) - exR) : 0;
    histC[t] = exC;                // scan base for scatter
    histR[t] = exR;
    __syncthreads();

    // ---- scatter phase: NO atomics (scan base + saved rank) ----
    #pragma unroll
    for (int k = 0; k < NITP; k++) {
        int i = t + k * TPB;
        if (i < cnt) {
            int p = histC[cb[k]] + rkC[k];
            stageC[p] = pk[k];
            bidC[p] = cb[k];
            int p2 = histR[rb[k]] + rkR[k];
            stageR[p2] = rpk[k];
            bidR[p2] = rb[k];
        }
    }
    __syncthreads();

    // ---- coalesced global write ----
    for (int p = t; p < cnt; p += TPB) {
        int b = bidC[p];
        int idx = gbaseC[b] + p;
        if (idx < (b + 1) * CAP) part[idx] = stageC[p];      // overflow clamp
        int b2 = bidR[p];
        int idx2 = gbaseR[b2] + p;
        if (idx2 < (b2 + 1) * CAP) partR[idx2] = stageR[p];
    }
}

// per FULL bucket (256 rows): count partR (uchar4, single scan) -> dinv + xs
__global__ __launch_bounds__(TPB)
void k_fillR(const unsigned char* __restrict__ partR, const int* __restrict__ bcurR,
             const float4* __restrict__ x4, float* __restrict__ dinv,
             unsigned short* __restrict__ xs, int n) {
    __shared__ int lcnt[BCOLS];
    __shared__ float ldinv[BCOLS];
    int b = blockIdx.x;
    int s = b * CAP;               // CAP multiple of 4 -> uchar4-aligned
    int t = threadIdx.x;           // TPB = 512
    int cntR = min(bcurR[b], CAP);
    if (t < BCOLS) lcnt[t] = 0;
    __syncthreads();
    int c4 = cntR >> 2;
    const uchar4* p4 = (const uchar4*)(partR + s);
    for (int i = t; i < c4; i += TPB) {
        uchar4 kk = p4[i];
        atomicAdd(&lcnt[kk.x], 1);
        atomicAdd(&lcnt[kk.y], 1);
        atomicAdd(&lcnt[kk.z], 1);
        atomicAdd(&lcnt[kk.w], 1);
    }
    for (int i = (c4 << 2) + t; i < cntR; i += TPB)
        atomicAdd(&lcnt[partR[s + i]], 1);
    __syncthreads();
    int rows_base = b << BSHIFT;
    if (t < BCOLS) {
        float d = rsqrtf((float)(lcnt[t] + 1));      // +1 self loop
        ldinv[t] = d;
        int gr = rows_base + t;
        if (gr < n) dinv[gr] = d;
    }
    __syncthreads();
    int nr = n - rows_base;
    if (nr <= 0) return;
    size_t base4 = (size_t)rows_base << 4;           // float4 idx of first row
    int lim = min(BCOLS, nr) << 4;
    for (int i = t; i < lim; i += TPB) {
        float dd = ldinv[i >> 4];
        float4 vv = x4[base4 + i];
        ushort4 o;
        o.x = f2bf(dd * vv.x); o.y = f2bf(dd * vv.y);
        o.z = f2bf(dd * vv.z); o.w = f2bf(dd * vv.w);
        ((ushort4*)xs)[base4 + i] = o;
    }
}

#define XSLD(r) (*((const uint4*)(xs + ((size_t)(r) << 6)) + li))
#define ACC8(u) { a0 += bflo(u.x); a1 += bfhi(u.x); \
                  a2 += bflo(u.y); a3 += bfhi(u.y); \
                  a4 += bflo(u.z); a5 += bfhi(u.z); \
                  a6 += bflo(u.w); a7 += bfhi(u.w); }

// per FULL bucket (256 cols): single part scan, rank-reuse 256-bin CSR in
// LDS, then 4-deep-MLP gather: 64 groups x 8 lanes, 4 cols per group.
__global__ __launch_bounds__(TPB)
void k_fuse(const int* __restrict__ part, const int* __restrict__ bcur,
            const unsigned short* __restrict__ xs,
            const float* __restrict__ dinv,
            float4* __restrict__ out4, int n) {
    __shared__ int lcnt[BCOLS];
    __shared__ int lps[BCOLS];
    __shared__ int wsum[4];
    __shared__ int stage[CAP];         // 20KB
    int b = blockIdx.x;
    int s = b * CAP;
    int cnt = min(bcur[b], CAP);
    int t = threadIdx.x;           // TPB = 512
    int lane = t & 63, wid = t >> 6;

    if (t < BCOLS) lcnt[t] = 0;
    __syncthreads();

    // ---- scan part once + count (rank = atomic return) ----
    int pk[FBIT];
    short rk[FBIT];
    #pragma unroll
    for (int k = 0; k < FBIT; k++) {
        int i = t + k * TPB;
        int v2 = (i < cnt) ? part[s + i] : -1;
        pk[k] = v2;
        rk[k] = -1;
        if (v2 >= 0)
            rk[k] = (short)atomicAdd(&lcnt[v2 >> 17], 1);
    }
    __syncthreads();

    // ---- 256-bin scan (4 waves) ----
    int v = 0, inc = 0;
    if (t < BCOLS) {
        v = lcnt[t];
        inc = wave_incl_scan(v, lane);
        if (lane == 63) wsum[wid] = inc;
    }
    __syncthreads();
    if (t < BCOLS) {
        int add = 0;
        if (wid > 0) add += wsum[0];
        if (wid > 1) add += wsum[1];
        if (wid > 2) add += wsum[2];
        lps[t] = inc - v + add;
    }
    __syncthreads();

    // ---- scatter: NO atomics (scan base + saved rank) ----
    #pragma unroll
    for (int k = 0; k < FBIT; k++) {
        if (rk[k] >= 0) {
            int v2 = pk[k];
            stage[lps[v2 >> 17] + rk[k]] = v2 & 0x1FFFF;   // pure row id
        }
    }
    __syncthreads();

    // ---- gather: 64 groups x 8 lanes; group gg owns cols {gg, gg+64, ...} ----
    int gg = t >> 3, li = t & 7;
    #pragma unroll
    for (int cc = 0; cc < BCOLS; cc += 64) {
        int c = cc + gg;
        int node = (b << BSHIFT) + c;
        if (node < n) {
            int ss = lps[c];
            int len = lcnt[c];
            float a0 = 0.f, a1 = 0.f, a2 = 0.f, a3 = 0.f;
            float a4 = 0.f, a5 = 0.f, a6 = 0.f, a7 = 0.f;
            int len4 = len & ~3;
            uint4 c0, c1, c2, c3;
            if (len4 > 0) {
                int r0 = stage[ss], r1 = stage[ss + 1];
                int r2 = stage[ss + 2], r3 = stage[ss + 3];
                c0 = XSLD(r0); c1 = XSLD(r1); c2 = XSLD(r2); c3 = XSLD(r3);
            }
            for (int i = 4; i < len4; i += 4) {
                int r0 = stage[ss + i],     r1 = stage[ss + i + 1];
                int r2 = stage[ss + i + 2], r3 = stage[ss + i + 3];
                uint4 n0 = XSLD(r0), n1 = XSLD(r1);
                uint4 n2 = XSLD(r2), n3 = XSLD(r3);
                ACC8(c0); ACC8(c1); ACC8(c2); ACC8(c3);
                c0 = n0; c1 = n1; c2 = n2; c3 = n3;
            }
            if (len4 > 0) { ACC8(c0); ACC8(c1); ACC8(c2); ACC8(c3); }
            for (int i = len4; i < len; i++) {
                int r = stage[ss + i];
                uint4 u = XSLD(r);
                ACC8(u);
            }
            // self term + scale + store
            float dc = dinv[node];
            uint4 us = XSLD(node);
            float4 r0o, r1o;
            r0o.x = dc * (a0 + bflo(us.x));
            r0o.y = dc * (a1 + bfhi(us.x));
            r0o.z = dc * (a2 + bflo(us.y));
            r0o.w = dc * (a3 + bfhi(us.y));
            r1o.x = dc * (a4 + bflo(us.z));
            r1o.y = dc * (a5 + bfhi(us.z));
            r1o.z = dc * (a6 + bflo(us.w));
            r1o.w = dc * (a7 + bfhi(us.w));
            size_t ob = ((size_t)node << 4) + (li << 1);
            out4[ob] = r0o;
            out4[ob + 1] = r1o;
        }
    }
}

extern "C" void kernel_launch(void* const* d_in, const int* in_sizes, int n_in,
                              void* d_out, int out_size, void* d_ws, size_t ws_size,
                              hipStream_t stream) {
    const float* x    = (const float*)d_in[0];
    const int*   eidx = (const int*)d_in[1];   // int32 (JAX x64 disabled)

    int n = in_sizes[0] / NFEAT;               // 100000
    int E = in_sizes[1] / 2;                   // 1600000
    const int* rows = eidx;
    const int* cols = eidx + E;
    float* out = (float*)d_out;

    int nbuck = (n + BCOLS - 1) >> BSHIFT;     // 391

    // ws: bcur[NBMAX] | bcurR[NBMAX] | dinv[n]
    //     | xs[n*64 bf16, 16B-aligned] | part[nbuck*CAP ints] | partR[uchar]
    char* w = (char*)d_ws;
    int*   bcur  = (int*)w;     w += NBMAX * 4;
    int*   bcurR = (int*)w;     w += NBMAX * 4;
    float* dinv  = (float*)w;   w += (size_t)n * 4;
    w = (char*)(((uintptr_t)w + 15) & ~(uintptr_t)15);
    unsigned short* xs = (unsigned short*)w;  w += (size_t)n * NFEAT * 2;
    int*   part  = (int*)w;     w += (size_t)nbuck * CAP * 4;
    unsigned char* partR = (unsigned char*)w;

    // zero cursors (zero-based; kernels add t*CAP) — graph-capturable
    hipMemsetAsync(bcur, 0, NBMAX * 2 * 4, stream);

    int nchunk = (E + CHUNK - 1) / CHUNK;      // 511
    k_partCR<<<nchunk, TPB, 0, stream>>>(rows, cols, bcur, bcurR,
                                         part, partR, E);
    k_fillR<<<nbuck, TPB, 0, stream>>>(partR, bcurR, (const float4*)x,
                                       dinv, xs, n);
    k_fuse<<<nbuck, TPB, 0, stream>>>(part, bcur, xs, dinv,
                                      (float4*)out, n);
}